// Round 9
// baseline (225.896 us; speedup 1.0000x reference)
//
#include <hip/hip_runtime.h>
#include <hip/hip_fp16.h>
#include <math.h>

#define B_    128
#define T_    24
#define NN    300
#define EE    9000
#define GG    (B_ * T_)
#define GRUH  12
#define OUTF  1200
#define NSPL  212      // rows 0..211 (largest after degree sort) get a helper lane
#define EVCAP (EE + NN)   // padded evals capacity (rows odd-padded: <= EE+NN)

// ---------------------------------------------------------------------------
// Kernel 1: build degree-SORTED CSR of edges grouped by dst, with every row
// PADDED TO ODD LENGTH (len = deg | 1). Odd row stride makes gat_pool pass-2's
// per-lane b64 streams land on distinct banks (kills the structured 8-way
// conflict from uniform ~30-slot spacing). Dummy slots hold packed zeros.
// Outputs: row_ptr[NN+1] (padded, rank space), csr_pos[e] (padded slot of e).
// ---------------------------------------------------------------------------
__global__ __launch_bounds__(1024) void build_csr(
    const int* __restrict__ src, const int* __restrict__ dst,
    int* __restrict__ row_ptr, int* __restrict__ csr_pos)
{
    __shared__ int hist[16][512];          // 32 KB, wave w owns hist[w]
    __shared__ int cnt[512];
    __shared__ int rankv[512];
    __shared__ int bufA[512], bufB[512];
    const int tid  = threadIdx.x;
    const int wave = tid >> 6;
    (void)src;

    for (int i = tid; i < 16 * 512; i += 1024) ((int*)hist)[i] = 0;
    __syncthreads();

    for (int e = tid; e < EE; e += 1024) atomicAdd(&hist[wave][dst[e]], 1);
    __syncthreads();

    if (tid < 512) {
        int s = 0;
#pragma unroll
        for (int w = 0; w < 16; w++) { int t = hist[w][tid]; hist[w][tid] = s; s += t; }
        cnt[tid] = s;
    }
    __syncthreads();

    // rank nodes by descending degree (ties by id)
    if (tid < NN) {
        const int d = cnt[tid];
        int r = 0;
        for (int m = 0; m < NN; m++) {
            const int dm = cnt[m];
            r += (dm > d) || (dm == d && m < tid);
        }
        rankv[tid] = r;
    }
    if (tid < 512) bufA[tid] = 0;
    __syncthreads();
    if (tid < NN) bufA[rankv[tid]] = cnt[tid] | 1;   // odd-padded length
    __syncthreads();

    int* cur = bufA; int* nxt = bufB;
    for (int d = 1; d < 512; d <<= 1) {
        if (tid < 512) nxt[tid] = cur[tid] + (tid >= d ? cur[tid - d] : 0);
        __syncthreads();
        int* t = cur; cur = nxt; nxt = t;
    }
    if (tid <= NN) row_ptr[tid] = (tid == 0) ? 0 : cur[tid - 1];

    if (tid < 512) {
        int base = 0;
        if (tid < NN) { const int r = rankv[tid]; base = (r == 0) ? 0 : cur[r - 1]; }
#pragma unroll
        for (int w = 0; w < 16; w++) hist[w][tid] += base;
    }
    __syncthreads();

    for (int e = tid; e < EE; e += 1024) {
        const int d = dst[e];
        const int pos = atomicAdd(&hist[wave][d], 1);
        csr_pos[e] = pos;
    }
}

// ---------------------------------------------------------------------------
// Kernel 2: per-graph EdgeGAT + mean pool -> scalar S[g]. ONE pass over ew.
//  zero-fill padded evals (b128 sequential, trivial) ->
//  pass 1: statically flattened quads; packs half2(ex, ex*x_src) -> 4B
//          scatter to evals[csr_pos[e]]; dummies stay 0 (add nothing).
//  pass 2: degree-balanced + helper-split; sequential b64 reads over
//          ODD-stride rows (bank-spread), register accumulation.
// LDS ~40.1 KB -> still 4 blocks/CU (512 thr: thread-slot capped at 4).
// ---------------------------------------------------------------------------
__global__ __launch_bounds__(512) void gat_pool(
    const float* __restrict__ x, const float* __restrict__ ew,
    const int* __restrict__ src, const int* __restrict__ dst,
    const float* __restrict__ w_node, const float* __restrict__ w_edge,
    const float* __restrict__ attn_l, const float* __restrict__ attn_r,
    const float* __restrict__ attn_e,
    const int* __restrict__ row_ptr, const int* __restrict__ csr_pos,
    float* __restrict__ S)
{
    __shared__ float xs[NN];
    __shared__ __align__(16) unsigned int evals[EVCAP];  // half2(ex, ex*x_src)
    __shared__ float2 part[NSPL];
    __shared__ float red[8];

    const int g = blockIdx.x;
    const int tid = threadIdx.x;

    float cL = 0.f, cR = 0.f, cE = 0.f;
#pragma unroll
    for (int o = 0; o < 4; o++) {
        float wn = w_node[o];
        cL += wn * attn_l[o];
        cR += wn * attn_r[o];
        cE += w_edge[o] * attn_e[o];
    }

    const float* xrow = x + (size_t)g * NN;
    const float* erow = ew + (size_t)g * EE;

    // zero padded evals (EVCAP = 9300, divisible by 4) + stage xs
    for (int i = tid; i < EVCAP / 4; i += 512)
        ((uint4*)evals)[i] = make_uint4(0u, 0u, 0u, 0u);
    if (tid < NN / 4) ((float4*)xs)[tid] = ((const float4*)xrow)[tid];
    __syncthreads();

    const float4* __restrict__ erow4 = (const float4*)erow;
    const int4*   __restrict__ src4  = (const int4*)src;
    const int4*   __restrict__ dst4  = (const int4*)dst;
    const int4*   __restrict__ pos4  = (const int4*)csr_pos;

#define PROCQ(e4, s4, d4, p4)                                        \
    {                                                                \
        const float xa = xs[s4.x], xb = xs[s4.y];                    \
        const float xc = xs[s4.z], xd = xs[s4.w];                    \
        const float ya = xs[d4.x], yb = xs[d4.y];                    \
        const float yc = xs[d4.z], yd = xs[d4.w];                    \
        float v0 = fmaf(cL, xa, fmaf(cR, ya, cE * e4.x));            \
        float v1 = fmaf(cL, xb, fmaf(cR, yb, cE * e4.y));            \
        float v2 = fmaf(cL, xc, fmaf(cR, yc, cE * e4.z));            \
        float v3 = fmaf(cL, xd, fmaf(cR, yd, cE * e4.w));            \
        v0 = fminf((v0 >= 0.f) ? v0 : 0.2f * v0, 11.0f);             \
        v1 = fminf((v1 >= 0.f) ? v1 : 0.2f * v1, 11.0f);             \
        v2 = fminf((v2 >= 0.f) ? v2 : 0.2f * v2, 11.0f);             \
        v3 = fminf((v3 >= 0.f) ? v3 : 0.2f * v3, 11.0f);             \
        const float ex0 = __expf(v0), ex1 = __expf(v1);              \
        const float ex2 = __expf(v2), ex3 = __expf(v3);              \
        union { __half2 h2; unsigned int u; } c0, c1, c2, c3;        \
        c0.h2 = __halves2half2(__float2half_rn(ex0), __float2half_rn(ex0 * xa)); \
        c1.h2 = __halves2half2(__float2half_rn(ex1), __float2half_rn(ex1 * xb)); \
        c2.h2 = __halves2half2(__float2half_rn(ex2), __float2half_rn(ex2 * xc)); \
        c3.h2 = __halves2half2(__float2half_rn(ex3), __float2half_rn(ex3 * xd)); \
        evals[p4.x] = c0.u; evals[p4.y] = c1.u;                      \
        evals[p4.z] = c2.u; evals[p4.w] = c3.u;                      \
    }

    // 2250 quads = 4*512 + 202, statically flattened for MLP
    {
        const int qa = tid, qb = tid + 512;
        const float4 eA = erow4[qa]; const int4 sA = src4[qa];
        const int4   dA = dst4[qa];  const int4 pA = pos4[qa];
        const float4 eB = erow4[qb]; const int4 sB = src4[qb];
        const int4   dB = dst4[qb];  const int4 pB = pos4[qb];
        PROCQ(eA, sA, dA, pA);
        PROCQ(eB, sB, dB, pB);
    }
    {
        const int qa = tid + 1024, qb = tid + 1536;
        const float4 eA = erow4[qa]; const int4 sA = src4[qa];
        const int4   dA = dst4[qa];  const int4 pA = pos4[qa];
        const float4 eB = erow4[qb]; const int4 sB = src4[qb];
        const int4   dB = dst4[qb];  const int4 pB = pos4[qb];
        PROCQ(eA, sA, dA, pA);
        PROCQ(eB, sB, dB, pB);
    }
    if (tid < 2250 - 2048) {
        const int qa = tid + 2048;
        const float4 eA = erow4[qa]; const int4 sA = src4[qa];
        const int4   dA = dst4[qa];  const int4 pA = pos4[qa];
        PROCQ(eA, sA, dA, pA);
    }
#undef PROCQ
    __syncthreads();

    // pass 2: primary lanes 0-299 (row = tid); helper lanes 300-511 take the
    // second half of rows 0-211. Sequential b64 reads (odd row stride ->
    // bank-spread), register accumulation. Dummy slots add exact 0.
    const bool isHelper = (tid >= NN);
    const int  row      = isHelper ? (tid - NN) : tid;
    float den = 0.f, num = 0.f;
    if (tid < NN + NSPL) {
        const int beg = row_ptr[row];
        const int end = row_ptr[row + 1];
        const bool split = (row < NSPL);
        int lo = beg, hi = end;
        if (split) {
            const int mid = (beg + end) >> 1;
            lo = isHelper ? mid : beg;
            hi = isHelper ? end : mid;
        }
        int i = lo;
        if ((i & 1) && i < hi) {
            union { unsigned int u; __half2 h2; } c; c.u = evals[i++];
            const float2 f = __half22float2(c.h2);
            den += f.x; num += f.y;
        }
        for (; i + 4 <= hi; i += 4) {
            const uint2 a = *(const uint2*)(evals + i);
            const uint2 b = *(const uint2*)(evals + i + 2);
            union { unsigned int u; __half2 h2; } c0, c1, c2, c3;
            c0.u = a.x; c1.u = a.y; c2.u = b.x; c3.u = b.y;
            const float2 f0 = __half22float2(c0.h2);
            const float2 f1 = __half22float2(c1.h2);
            const float2 f2 = __half22float2(c2.h2);
            const float2 f3 = __half22float2(c3.h2);
            den += (f0.x + f1.x) + (f2.x + f3.x);
            num += (f0.y + f1.y) + (f2.y + f3.y);
        }
        for (; i < hi; i++) {
            union { unsigned int u; __half2 h2; } c; c.u = evals[i];
            const float2 f = __half22float2(c.h2);
            den += f.x; num += f.y;
        }
        if (isHelper) part[row] = make_float2(den, num);
    }
    __syncthreads();

    float acc = 0.f;
    if (tid < NN) {
        if (row < NSPL) { den += part[row].x; num += part[row].y; }
        if (den > 0.f) acc = num / den;   // padded empty row -> den==0 -> 0
    }

    // block reduce (8 waves)
    for (int off = 32; off > 0; off >>= 1) acc += __shfl_down(acc, off);
    if ((tid & 63) == 0) red[tid >> 6] = acc;
    __syncthreads();
    if (tid == 0) {
        float s = 0.f;
#pragma unroll
        for (int w = 0; w < 8; w++) s += red[w];
        S[g] = s;
    }
}

// ---------------------------------------------------------------------------
// Kernel 3: fused GRU (wave 0, shuffle-only, 0 barriers in time loop) +
// FC 12->1200 across 256 threads with float4 weight rows.
// pooled[b,t,o] = (S[g]/N) * w_node[o] + gat_bias[o]
// ---------------------------------------------------------------------------
__device__ __forceinline__ float sigmoidf_(float v) { return 1.0f / (1.0f + __expf(-v)); }

__global__ __launch_bounds__(256) void gru_fc(
    const float* __restrict__ S,
    const float* __restrict__ w_node, const float* __restrict__ gat_bias,
    const float* __restrict__ w_ih, const float* __restrict__ w_hh,
    const float* __restrict__ b_ih, const float* __restrict__ b_hh,
    const float* __restrict__ fc_w, const float* __restrict__ fc_b,
    float* __restrict__ out)
{
    __shared__ float hsh[GRUH];
    const int b = blockIdx.x;
    const int tid = threadIdx.x;

    if (tid < 64) {
        float wn[4], gb[4];
#pragma unroll
        for (int i = 0; i < 4; i++) {
            wn[i] = w_node[i] * (1.0f / (float)NN);
            gb[i] = gat_bias[i];
        }
        float wih[4] = {0.f, 0.f, 0.f, 0.f};
        float whh[12];
#pragma unroll
        for (int j = 0; j < 12; j++) whh[j] = 0.f;
        float bih = 0.f, bhh = 0.f;
        if (tid < 36) {
#pragma unroll
            for (int i = 0; i < 4; i++)  wih[i] = w_ih[tid * 4 + i];
#pragma unroll
            for (int j = 0; j < 12; j++) whh[j] = w_hh[tid * 12 + j];
            bih = b_ih[tid];
            bhh = b_hh[tid];
        }
        float srow = (tid < T_) ? S[(size_t)b * T_ + tid] : 0.f;
        float hreg = 0.f;
        const int l = tid % 12;
        for (int t = 0; t < T_; t++) {
            float Sg = __shfl(srow, t);
            float gi = bih, gh = bhh;
#pragma unroll
            for (int i = 0; i < 4; i++) gi += (Sg * wn[i] + gb[i]) * wih[i];
#pragma unroll
            for (int j = 0; j < 12; j++) gh += __shfl(hreg, j) * whh[j];
            float a   = gi + gh;
            float aiz = __shfl(a, 12 + l);
            float gin = __shfl(gi, 24 + l);
            float ghn = __shfl(gh, 24 + l);
            if (tid < 12) {
                float r = sigmoidf_(a);
                float z = sigmoidf_(aiz);
                float n = tanhf(gin + r * ghn);
                hreg = (1.f - z) * n + z * hreg;
            }
        }
        if (tid < GRUH) hsh[tid] = hreg;
    }
    __syncthreads();

    float h0 = hsh[0], h1 = hsh[1], h2 = hsh[2],  h3 = hsh[3];
    float h4 = hsh[4], h5 = hsh[5], h6 = hsh[6],  h7 = hsh[7];
    float h8 = hsh[8], h9 = hsh[9], hA = hsh[10], hB = hsh[11];
    for (int j = tid; j < OUTF; j += 256) {
        const float4* w4 = (const float4*)(fc_w + (size_t)j * GRUH);
        const float4 a = w4[0], c = w4[1], d = w4[2];
        float o = fc_b[j];
        o += h0 * a.x + h1 * a.y + h2 * a.z + h3 * a.w;
        o += h4 * c.x + h5 * c.y + h6 * c.z + h7 * c.w;
        o += h8 * d.x + h9 * d.y + hA * d.z + hB * d.w;
        out[(size_t)b * OUTF + j] = o;
    }
}

// ---------------------------------------------------------------------------
extern "C" void kernel_launch(void* const* d_in, const int* in_sizes, int n_in,
                              void* d_out, int out_size, void* d_ws, size_t ws_size,
                              hipStream_t stream)
{
    const float* x        = (const float*)d_in[0];
    const float* ew       = (const float*)d_in[1];
    const int*   src      = (const int*)d_in[2];
    const int*   dst      = (const int*)d_in[3];
    const float* w_node   = (const float*)d_in[4];
    const float* w_edge   = (const float*)d_in[5];
    const float* attn_l   = (const float*)d_in[6];
    const float* attn_r   = (const float*)d_in[7];
    const float* attn_e   = (const float*)d_in[8];
    const float* gat_bias = (const float*)d_in[9];
    const float* w_ih     = (const float*)d_in[10];
    const float* w_hh     = (const float*)d_in[11];
    const float* b_ih     = (const float*)d_in[12];
    const float* b_hh     = (const float*)d_in[13];
    const float* fc_w     = (const float*)d_in[14];
    const float* fc_b     = (const float*)d_in[15];
    float* out = (float*)d_out;

    // workspace: S[GG] f32 | row_ptr[304] | csr_pos[EE]  (~50 KB)
    char* ws = (char*)d_ws;
    float* S       = (float*)ws;
    int*   row_ptr = (int*)(ws + GG * 4);
    int*   csr_pos = row_ptr + 304;

    build_csr<<<1, 1024, 0, stream>>>(src, dst, row_ptr, csr_pos);
    gat_pool<<<GG, 512, 0, stream>>>(x, ew, src, dst, w_node, w_edge,
                                     attn_l, attn_r, attn_e,
                                     row_ptr, csr_pos, S);
    gru_fc<<<B_, 256, 0, stream>>>(S, w_node, gat_bias, w_ih, w_hh,
                                   b_ih, b_hh, fc_w, fc_b, out);
}